// Round 4
// baseline (390.518 us; speedup 1.0000x reference)
//
#include <hip/hip_runtime.h>
#include <math.h>

#define HSZ 8192
#define ISZ 4096
#define OSZ 4096
#define NTOT (HSZ + OSZ)
#define STEPS 100
#define SIMB (NTOT / 64)   // 192 sim blocks of 64 threads; block SIMB does the loss

__device__ __forceinline__ float bf2f(unsigned short h) {
    union { unsigned u; float f; } c; c.u = ((unsigned)h) << 16; return c.f;
}

// unpack a uint holding two packed bf16 (little-endian: low ushort = even elem)
__device__ __forceinline__ float2 upk(unsigned u) {
    union { unsigned q; float f; } lo, hi;
    lo.q = u << 16; hi.q = u & 0xffff0000u;
    float2 r; r.x = lo.f; r.y = hi.f; return r;
}

__device__ __forceinline__ double compress_d(double x, double gain) {
    // sign(x) * log1p(gain*|x| + 1e-6), sign(0)==0
    double s = (x > 0.0) ? 1.0 : ((x < 0.0) ? -1.0 : 0.0);
    return s * log1p(gain * fabs(x) + 1e-6);
}

__device__ __forceinline__ double wred(double a) {
    #pragma unroll
    for (int o = 32; o > 0; o >>= 1) a += __shfl_down(a, o, 64);
    return a;
}

// dtype probe: W1 ~ U(0, 0.05). bf16 data => every ushort decodes to |x| <= 0.0625.
// fp32 data read as ushorts => even halves are random-exponent garbage, some > 0.0625.
// Wave-uniform result, ~60 cycles, 256 B from L2 — cheap enough to run per block.
__device__ __forceinline__ int detect_bf16(const void* W1) {
    const unsigned short* p = (const unsigned short*)W1;
    const int lane = threadIdx.x & 63;
    unsigned short a0 = (unsigned short)(p[lane] & 0x7FFF);
    unsigned short a1 = (unsigned short)(p[lane + 64] & 0x7FFF);
    unsigned long long bad = __ballot((a0 > 0x3D80) || (a1 > 0x3D80));
    return bad == 0ull;
}

// One wave per row, 4 rows per 256-thread block. Exact f64 dot.
// XIN=1: x has the input dtype; XIN=0: x is internal fp32 (workspace).
// FB=0:  y[row] = compress(dot, gain)
// FB=1:  y[row] = prev[row] - dot
template <int C, int XIN, int FB>
__global__ __launch_bounds__(256) void mv_kernel(const void* __restrict__ W,
                                                 const void* __restrict__ x,
                                                 const void* __restrict__ gain,
                                                 const float* __restrict__ prev,
                                                 float* __restrict__ y,
                                                 const void* __restrict__ W1ref) {
    const int wave = threadIdx.x >> 6, lane = threadIdx.x & 63;
    const int row  = blockIdx.x * 4 + wave;
    const int bf   = detect_bf16(W1ref);
    double acc = 0.0;
    if (bf) {
        // 16 B/lane: uint4 = 8 bf16 per lane per iter, 512 elems per wave-iter
        const uint4* Wr = (const uint4*)((const unsigned short*)W + (size_t)row * C);
        #pragma unroll
        for (int it = 0; it < C / 512; ++it) {
            const int i = it * 64 + lane;
            uint4 w = Wr[i];
            float2 w0 = upk(w.x), w1 = upk(w.y), w2 = upk(w.z), w3 = upk(w.w);
            float x0, x1, x2, x3, x4, x5, x6, x7;
            if (XIN) {
                uint4 xx = ((const uint4*)x)[i];
                float2 p0 = upk(xx.x), p1 = upk(xx.y), p2 = upk(xx.z), p3 = upk(xx.w);
                x0 = p0.x; x1 = p0.y; x2 = p1.x; x3 = p1.y;
                x4 = p2.x; x5 = p2.y; x6 = p3.x; x7 = p3.y;
            } else {
                const float4* xv = (const float4*)x;
                float4 xa = xv[i * 2], xb = xv[i * 2 + 1];
                x0 = xa.x; x1 = xa.y; x2 = xa.z; x3 = xa.w;
                x4 = xb.x; x5 = xb.y; x6 = xb.z; x7 = xb.w;
            }
            acc += (double)w0.x * x0 + (double)w0.y * x1;
            acc += (double)w1.x * x2 + (double)w1.y * x3;
            acc += (double)w2.x * x4 + (double)w2.y * x5;
            acc += (double)w3.x * x6 + (double)w3.y * x7;
        }
    } else {
        // fp32 fallback: float4 = 16 B/lane, 256 elems per wave-iter
        const float4* Wr = (const float4*)((const float*)W + (size_t)row * C);
        const float4* xv = (const float4*)x;   // x is fp32 in both XIN cases here
        #pragma unroll
        for (int it = 0; it < C / 256; ++it) {
            const int i = it * 64 + lane;
            float4 w = Wr[i], xx = xv[i];
            acc += (double)w.x * (double)xx.x + (double)w.y * (double)xx.y;
            acc += (double)w.z * (double)xx.z + (double)w.w * (double)xx.w;
        }
    }
    acc = wred(acc);
    if (lane == 0) {
        if (FB) {
            y[row] = prev[row] - (float)acc;
        } else {
            float g = bf ? bf2f(*(const unsigned short*)gain) : *(const float*)gain;
            y[row] = (float)compress_d(acc, (double)g);
        }
    }
}

// Blocks 0..SIMB-1: Izhikevich Euler loop (fp32, jax op order), 1 wave/block.
// Block SIMB: loss = mean((io - target)^2) in f64.
__global__ __launch_bounds__(64) void sim_loss_kernel(const float* __restrict__ hid,
                                                      const float* __restrict__ io,
                                                      const void* __restrict__ tgt,
                                                      const void* __restrict__ W1ref,
                                                      float* __restrict__ out) {
    float* vout = out + 1;
    float* uout = out + 1 + (size_t)STEPS * NTOT;
    if (blockIdx.x == SIMB) {
        const int lane = threadIdx.x;
        const int bf = detect_bf16(W1ref);
        double acc = 0.0;
        for (int i = lane; i < OSZ; i += 64) {
            float t = bf ? bf2f(((const unsigned short*)tgt)[i]) : ((const float*)tgt)[i];
            double d = (double)io[i] - (double)t;
            acc += d * d;
        }
        acc = wred(acc);
        if (lane == 0) out[0] = (float)(acc / (double)OSZ);
        return;
    }
    const int n = blockIdx.x * 64 + threadIdx.x;
    const float ti = (n < HSZ) ? hid[n] : io[n - HSZ];
    float v = -65.0f;
    float u = -13.0f;              // 0.2f * -65.0f exactly
    vout[n] = v;
    uout[n] = u;
    for (int s = 1; s < STEPS; ++s) {
        // v + DT*(((((0.04*v^2) + 5.0*v) + 0.14) - u) + ti)   (jax fp32 op order)
        float dv = 0.04f * (v * v);
        dv = dv + 5.0f * v;
        dv = dv + 0.14f;
        dv = dv - u;
        dv = dv + ti;
        float vn = v + 1.0f * dv;
        float du = 0.2f * v - u;
        float un = u + 0.02f * du;
        bool sp = (vn >= 30.0f);
        v = sp ? -65.0f : vn;
        u = sp ? (un + 8.0f) : un;
        vout[(size_t)s * NTOT + n] = v;
        uout[(size_t)s * NTOT + n] = u;
    }
}

extern "C" void kernel_launch(void* const* d_in, const int* in_sizes, int n_in,
                              void* d_out, int out_size, void* d_ws, size_t ws_size,
                              hipStream_t stream) {
    const void* v_input = d_in[0];   // [ISZ]   input dtype
    const void* target  = d_in[1];   // [OSZ]   input dtype
    const void* W1      = d_in[2];   // [HSZ,ISZ]
    const void* W2      = d_in[3];   // [OSZ,HSZ]
    const void* Wfb     = d_in[4];   // [HSZ,OSZ]
    const void* gain1   = d_in[5];   // scalar
    const void* gain2   = d_in[6];   // scalar

    float* out = (float*)d_out;      // [0]=loss, then v_vec, then u_vec (fp32)

    float* h1c = (float*)d_ws;       // [HSZ]
    float* io  = h1c + HSZ;          // [OSZ]
    float* hid = io + OSZ;           // [HSZ]

    // 1) h1c = compress(W1 @ v_input, gain1)
    mv_kernel<ISZ, 1, 0><<<HSZ / 4, 256, 0, stream>>>(W1, v_input, gain1, nullptr, h1c, W1);
    // 2) io = compress(W2 @ h1c, gain2)
    mv_kernel<HSZ, 0, 0><<<OSZ / 4, 256, 0, stream>>>(W2, h1c, gain2, nullptr, io, W1);
    // 3) hid = h1c - Wfb @ io
    mv_kernel<OSZ, 0, 1><<<HSZ / 4, 256, 0, stream>>>(Wfb, io, nullptr, h1c, hid, W1);
    // 4) sim (blocks 0..191) + loss (block 192) in one dispatch
    sim_loss_kernel<<<SIMB + 1, 64, 0, stream>>>(hid, io, target, W1, out);
}